// Round 1
// baseline (91.050 us; speedup 1.0000x reference)
//
#include <hip/hip_runtime.h>
#include <math.h>

// Problem constants (from reference)
#define D 1024      // INPUT_SIZE
#define M 4096      // OUT_H * OUT_W
#define B 64        // BATCH
#define SOM_EPS 1e-6

typedef unsigned long long u64;

// ---------------------------------------------------------------------------
// Single fused kernel. Block d:
//   phase 1: per-row moments of w[d,:]  (bit-identical summation order to the
//            previous two-kernel version, so the double-precision argmin
//            ordering vs the exact-math reference is unchanged)
//   phase 2: wave 0, lane b computes dist2[b,d] = M*s^2 - 2*s*S1 + S2
//            (s = x[b,d]+eps) and folds it into a per-batch global argmin
//            with ONE agent-scope atomicMax on key = ~((bits(dist2)&~1023)|d).
//            For positive doubles the bit pattern is monotone, so max(~key)
//            selects lexicographic min of (truncated dist2, d) -- the d
//            tie-break matches argmin's first-occurrence rule.
//   epilogue: spin-free last-block detection. Every block drains vmcnt(0)
//            (its atomicMaxes are agent-scope RMWs performed at the coherence
//            point, so completion == global visibility), then one RELAXED
//            fetch_add on a counter. The 1024th adder reads the 64 final keys
//            (agent-scope loads) and writes all outputs. No spinning, no
//            threadfence/buffer_wbl2 traffic (what cost R2 ~50 us).
//
// Workspace init relies on the harness 0xAA poison (documented behavior,
// "poisoned to 0xAA before every timed launch"):
//   - minkey slots = 0xAAAA...AA, which is BELOW every real ~key (~0xBF8...),
//     so atomicMax needs no init pass (poison acts as the umax identity).
//   - counter = 0xAAAAAAAA, so the last adder sees old == 0xAAAAAAAA + 1023.
//     A zero-init fallback (old == 1023) and a winner self-reset (keys=0,
//     counter=0) keep replay-without-repoison correct as well.
// ---------------------------------------------------------------------------
__global__ __launch_bounds__(256) void som_fused(const float* __restrict__ x,
                                                 const float* __restrict__ w,
                                                 const float* __restrict__ loc,
                                                 float* __restrict__ out,
                                                 u64* __restrict__ minkey,     // 64 slots, 64 B apart
                                                 unsigned* __restrict__ counter) {
    const int d = blockIdx.x;
    const int t = threadIdx.x;

    // x-column prefetch for phase 2: lane b reads x[b, d] (stride-4KB gather;
    // each 64B line is shared by 16 consecutive blocks -> L2-friendly). Issued
    // first so its latency hides under the 16 KB row stream below.
    float xv = 0.0f;
    if (t < B) xv = x[t * D + d];

    // ---- phase 1: moments of row d (identical arithmetic to previous K1) ----
    const float4* row = (const float4*)(w + (size_t)d * M);
    double a1 = 0.0, a2 = 0.0;
#pragma unroll
    for (int k = 0; k < 4; ++k) {               // 4 * 256 float4 = 4096 floats
        float4 v = row[t + k * 256];
        double vx = v.x, vy = v.y, vz = v.z, vw = v.w;
        a1 += vx + vy + vz + vw;
        a2 += vx * vx + vy * vy + vz * vz + vw * vw;
    }
    for (int off = 32; off > 0; off >>= 1) {
        a1 += __shfl_down(a1, off);
        a2 += __shfl_down(a2, off);
    }
    __shared__ double l1[4], l2[4];
    const int wave = t >> 6, lane = t & 63;
    if (lane == 0) { l1[wave] = a1; l2[wave] = a2; }
    __syncthreads();

    // ---- phase 2: wave 0 only (64 lanes = 64 batches) ----
    if (t < B) {
        // same final summation order as previous K1 (l1[0]+l1[1]+l1[2]+l1[3])
        const double S1 = l1[0] + l1[1] + l1[2] + l1[3];
        const double S2 = l2[0] + l2[1] + l2[2] + l2[3];

        const double s  = (double)xv + SOM_EPS;
        const double bv = (double)M * s * s - 2.0 * s * S1 + S2;   // > 0 always

        // lexicographic (truncated dist2 bits, d); ~ turns umin into umax so
        // both the 0xAA poison and a 0 reset value act as the identity.
        const u64 key = ~(((u64)(long long)__double_as_longlong(bv) & ~1023ULL) | (u64)d);
        __hip_atomic_fetch_max(&minkey[t * 8], key,
                               __ATOMIC_RELAXED, __HIP_MEMORY_SCOPE_AGENT);

        // Completion == visibility for agent-scope RMWs: drain this wave's
        // vmcnt before signaling. No wbl2, no fences.
        asm volatile("s_waitcnt vmcnt(0)" ::: "memory");

        unsigned old = 0u;
        if (t == 0)
            old = __hip_atomic_fetch_add(counter, 1u,
                                         __ATOMIC_RELAXED, __HIP_MEMORY_SCOPE_AGENT);
        old = __shfl(old, 0);

        if (old == 0xAAAAAAAAu + (unsigned)(D - 1) || old == (unsigned)(D - 1)) {
            // Last block: every other block's maxes completed at the coherence
            // point before its counter add, so agent-scope loads see finals.
            const u64 kk = __hip_atomic_load(&minkey[t * 8],
                                             __ATOMIC_RELAXED, __HIP_MEMORY_SCOPE_AGENT);
            const u64 orig = ~kk;
            const int idx  = (int)(orig & 1023ULL);
            const double val = __longlong_as_double((long long)(orig & ~1023ULL));

            out[2 * t]     = loc[2 * idx];
            out[2 * t + 1] = loc[2 * idx + 1];

            double r = sqrt(val);      // truncation error ~2^-42 rel, invisible in f32
            for (int off = 32; off > 0; off >>= 1) r += __shfl_down(r, off);
            if (t == 0) out[2 * B] = (float)(r / (double)B);

            asm volatile("" ::: "memory");
            // self-reset so a replay without re-poison is still correct
            __hip_atomic_store(&minkey[t * 8], 0ULL,
                               __ATOMIC_RELAXED, __HIP_MEMORY_SCOPE_AGENT);
            if (t == 0)
                __hip_atomic_store(counter, 0u,
                                   __ATOMIC_RELAXED, __HIP_MEMORY_SCOPE_AGENT);
        }
    }
}

extern "C" void kernel_launch(void* const* d_in, const int* in_sizes, int n_in,
                              void* d_out, int out_size, void* d_ws, size_t ws_size,
                              hipStream_t stream) {
    const float* x   = (const float*)d_in[0];   // [B, D]
    const float* w   = (const float*)d_in[1];   // [D, M]
    const float* loc = (const float*)d_in[2];   // [M, 2]
    float* out = (float*)d_out;                 // [2*B locations, then loss]

    // ws layout: 64 argmin key slots padded to 64 B (4 KB), then the counter.
    u64*      minkey  = (u64*)d_ws;
    unsigned* counter = (unsigned*)((char*)d_ws + 64 * 64);

    som_fused<<<D, 256, 0, stream>>>(x, w, loc, out, minkey, counter);
}

// Round 2
// 77.704 us; speedup vs baseline: 1.1718x; 1.1718x over previous
//
#include <hip/hip_runtime.h>
#include <math.h>

// Problem constants (from reference)
#define D 1024      // INPUT_SIZE
#define M 4096      // OUT_H * OUT_W
#define B 64        // BATCH
#define SOM_EPS 1e-6
#define G 4                  // weight rows per block
#define NBLK (D / G)         // 256 blocks -> one per CU, 16 waves each

typedef unsigned long long u64;

// ---------------------------------------------------------------------------
// Single fused kernel, contention-free cross-block reduction.
//
// Round-1 post-mortem: fusion itself was right (one launch gap + one
// end-of-kernel drain saved) but 65536 agent-scope atomicMax RMWs onto 64
// lines serialized at the coherence point (~1024 x ~25ns per line) and cost
// ~+15us. This version keeps the exact same (proven-correct, absmax 0.0)
// memory-model protocol but with DISTINCT-address plain stores:
//
//   block blk (owns rows d0..d0+3):
//     phase 1: per-row moments, bit-identical summation order to the
//              original two-kernel version (row = 256 threads / 4 waves,
//              final S = l[4g]+l[4g+1]+l[4g+2]+l[4g+3]).
//     phase 2: wave 0, lane b folds the 4 rows into ONE key
//              key = (bits(dist2) & ~1023) | d   (lexicographic min ==
//              (dist2, first d) argmin; low-10-bit truncation already
//              verified absmax 0.0 in round 1), then one coalesced
//              agent-scope relaxed store to kbuf[blk*64+b]. Zero contention.
//     epilogue: vmcnt(0) drain (agent-scope stores complete at the
//              coherence point => globally visible), ONE relaxed fetch_add
//              (256 total -> negligible). Last finisher min-reduces the
//              256x64 key array with all 1024 threads and writes outputs.
//              No spinning, no threadfence/buffer_wbl2, no contended RMWs.
//
// Poison handling: counter starts 0xAAAAAAAA (documented 0xAA poison), so
// last old == 0xAAAAAAAA+255; zero-start fallback (old==255) + winner
// self-reset keeps replay-without-repoison correct. kbuf needs no init:
// every slot is written by its owner before that owner increments counter.
// ---------------------------------------------------------------------------
__global__ __launch_bounds__(1024) void som_onepass(const float* __restrict__ x,
                                                    const float* __restrict__ w,
                                                    const float* __restrict__ loc,
                                                    float* __restrict__ out,
                                                    u64* __restrict__ kbuf,     // [NBLK][B]
                                                    unsigned* __restrict__ counter) {
    const int blk = blockIdx.x;
    const int t   = threadIdx.x;
    const int d0  = blk * G;

    __shared__ float  xs[G * B];        // xs[g*64+b] = x[b, d0+g]
    __shared__ double l1[16], l2[16];   // per-wave partials (16 waves)
    __shared__ u64    red[1024];        // last-block reduce scratch
    __shared__ unsigned oldsh;

    // x gather for phase 2 (64 lines, issued first so latency hides under
    // the 64 KB row stream below)
    if (t < G * B) {
        const int gg = t >> 6, b = t & 63;
        xs[t] = x[b * D + d0 + gg];
    }

    // ---- phase 1: moments; row g handled by waves 4g..4g+3 ----
    const int g = t >> 8;               // row within block
    const int u = t & 255;              // thread within row
    const float4* row = (const float4*)(w + (size_t)(d0 + g) * M);
    double a1 = 0.0, a2 = 0.0;
#pragma unroll
    for (int k = 0; k < 4; ++k) {       // 4 * 256 float4 = 4096 floats/row
        float4 v = row[u + k * 256];
        double vx = v.x, vy = v.y, vz = v.z, vw = v.w;
        a1 += vx + vy + vz + vw;
        a2 += vx * vx + vy * vy + vz * vz + vw * vw;
    }
    for (int off = 32; off > 0; off >>= 1) {
        a1 += __shfl_down(a1, off);
        a2 += __shfl_down(a2, off);
    }
    const int wave = t >> 6, lane = t & 63;
    if (lane == 0) { l1[wave] = a1; l2[wave] = a2; }
    __syncthreads();

    // ---- phase 2: wave 0, lane b = t folds G rows into one key ----
    if (t < B) {
        u64 best = ~0ULL;
#pragma unroll
        for (int gg = 0; gg < G; ++gg) {
            // same final summation order as the verified two-kernel version
            const double S1 = l1[4*gg] + l1[4*gg+1] + l1[4*gg+2] + l1[4*gg+3];
            const double S2 = l2[4*gg] + l2[4*gg+1] + l2[4*gg+2] + l2[4*gg+3];
            const double s  = (double)xs[gg * 64 + t] + SOM_EPS;
            const double bv = (double)M * s * s - 2.0 * s * S1 + S2;   // > 0
            const u64 key = (((u64)__double_as_longlong(bv)) & ~1023ULL)
                          | (u64)(d0 + gg);
            if (key < best) best = key;     // ascending gg => first-occurrence
        }
        // distinct addresses, coalesced 512B per block: zero contention
        __hip_atomic_store(&kbuf[blk * B + t], best,
                           __ATOMIC_RELAXED, __HIP_MEMORY_SCOPE_AGENT);
        // completion == visibility for agent-scope accesses at the coherence
        // point; drain before signaling (proven protocol, round 1)
        asm volatile("s_waitcnt vmcnt(0)" ::: "memory");
        if (t == 0)
            oldsh = __hip_atomic_fetch_add(counter, 1u,
                                           __ATOMIC_RELAXED, __HIP_MEMORY_SCOPE_AGENT);
    }
    __syncthreads();
    const unsigned old = oldsh;

    if (old == 0xAAAAAAAAu + (unsigned)(NBLK - 1) || old == (unsigned)(NBLK - 1)) {
        // Last finisher: every other block's stores reached the coherence
        // point before its counter add. Reduce 256x64 keys with 1024 threads.
        const int b = t & 63, c = t >> 6;       // 16 chunks x 64 batches
        u64 m = ~0ULL;
        for (int j = c; j < NBLK; j += 16) {
            const u64 k = __hip_atomic_load(&kbuf[j * B + b],
                                            __ATOMIC_RELAXED, __HIP_MEMORY_SCOPE_AGENT);
            if (k < m) m = k;
        }
        red[c * 64 + b] = m;
        __syncthreads();                         // block-uniform branch: legal
        if (t < B) {
            u64 m2 = red[t];
            for (int c2 = 1; c2 < 16; ++c2) {
                const u64 k = red[c2 * 64 + t];
                if (k < m2) m2 = k;
            }
            const int    idx = (int)(m2 & 1023ULL);
            const double val = __longlong_as_double((long long)(m2 & ~1023ULL));

            out[2 * t]     = loc[2 * idx];
            out[2 * t + 1] = loc[2 * idx + 1];

            double r = sqrt(val);   // trunc err ~2^-42 rel, invisible in f32
            for (int off = 32; off > 0; off >>= 1) r += __shfl_down(r, off);
            if (t == 0) {
                out[2 * B] = (float)(r / (double)B);
                // self-reset so replay without re-poison still works
                __hip_atomic_store(counter, 0u,
                                   __ATOMIC_RELAXED, __HIP_MEMORY_SCOPE_AGENT);
            }
        }
    }
}

extern "C" void kernel_launch(void* const* d_in, const int* in_sizes, int n_in,
                              void* d_out, int out_size, void* d_ws, size_t ws_size,
                              hipStream_t stream) {
    const float* x   = (const float*)d_in[0];   // [B, D]
    const float* w   = (const float*)d_in[1];   // [D, M]
    const float* loc = (const float*)d_in[2];   // [M, 2]
    float* out = (float*)d_out;                 // [2*B locations, then loss]

    // ws layout: kbuf[NBLK*B] u64 (128 KB), then counter (u32)
    u64*      kbuf    = (u64*)d_ws;
    unsigned* counter = (unsigned*)((char*)d_ws + (size_t)NBLK * B * sizeof(u64));

    som_onepass<<<NBLK, 1024, 0, stream>>>(x, w, loc, out, kbuf, counter);
}

// Round 3
// 75.039 us; speedup vs baseline: 1.2134x; 1.0355x over previous
//
#include <hip/hip_runtime.h>
#include <math.h>

// Problem constants (from reference)
#define D 1024      // INPUT_SIZE
#define M 4096      // OUT_H * OUT_W
#define B 64        // BATCH
#define SOM_EPS 1e-6

// Two kernels; the kernel boundary is the producer->consumer barrier (the
// command processor's end-of-kernel cache maintenance makes K1's stores
// visible to K2 on all XCDs). Session evidence:
//   R1 (fused, contended agent atomicMax): 91.1 us  (+15 us RMW serialization)
//   R2 (fused, distinct-slot stores):      77.7 us  (finisher tail == saved gap)
//   two-kernel:                            76.5 us  <- best; restored here
//
// Algebra: dist2[b,d] = sum_m (s - w[d,m])^2 = M*s^2 - 2*s*S1[d] + S2[d],
// s = x[b,d] + eps. All moment/argmin math in double so the argmin ordering
// matches the exact-math (np reference) argmin bit-for-bit.

// ---------------------------------------------------------------------------
// K1: per-row moments of weight [D, M]; block d -> S1[d], S2[d].
// Also zeroes the loss accumulator + done counter (ws is poisoned to 0xAA
// before every timed launch; stream order publishes the zeros to K2).
// ---------------------------------------------------------------------------
__global__ __launch_bounds__(256) void som_stats(const float* __restrict__ w,
                                                 double* __restrict__ S1,
                                                 double* __restrict__ S2,
                                                 double* __restrict__ acc,
                                                 unsigned* __restrict__ counter) {
    const int d = blockIdx.x;
    const int t = threadIdx.x;
    const float4* row = (const float4*)(w + (size_t)d * M);

    double a1 = 0.0, a2 = 0.0;
#pragma unroll
    for (int k = 0; k < 4; ++k) {               // 4 * 256 float4 = 4096 floats
        float4 v = row[t + k * 256];
        double vx = v.x, vy = v.y, vz = v.z, vw = v.w;
        a1 += vx + vy + vz + vw;
        a2 += vx * vx + vy * vy + vz * vz + vw * vw;
    }
    for (int off = 32; off > 0; off >>= 1) {
        a1 += __shfl_down(a1, off);
        a2 += __shfl_down(a2, off);
    }
    __shared__ double l1[4], l2[4];
    const int wave = t >> 6, lane = t & 63;
    if (lane == 0) { l1[wave] = a1; l2[wave] = a2; }
    __syncthreads();
    if (t == 0) {
        S1[d] = l1[0] + l1[1] + l1[2] + l1[3];
        S2[d] = l2[0] + l2[1] + l2[2] + l2[3];
        if (d == 0) { *acc = 0.0; *counter = 0u; }   // un-poison reduction state
    }
}

// ---------------------------------------------------------------------------
// K2: block b computes the double-precision argmin over d, writes the two
// location floats, atomically accumulates sqrt(min) into acc, and the last
// block to finish writes out[2B] = acc / B.
// ---------------------------------------------------------------------------
__global__ __launch_bounds__(1024) void som_argmin_loss(const float* __restrict__ x,
                                                        const double* __restrict__ S1,
                                                        const double* __restrict__ S2,
                                                        const float* __restrict__ loc,
                                                        float* __restrict__ out,
                                                        double* __restrict__ acc,
                                                        unsigned* __restrict__ counter) {
    const int b = blockIdx.x;
    const int t = threadIdx.x;

    double s = (double)x[b * D + t] + SOM_EPS;
    double bv = (double)M * s * s - 2.0 * s * S1[t] + S2[t];
    int bi = t;

    // wave (64-lane) argmin; tie-break keeps lower index (first occurrence)
    for (int off = 32; off > 0; off >>= 1) {
        double ov = __shfl_down(bv, off);
        int    oi = __shfl_down(bi, off);
        if (ov < bv || (ov == bv && oi < bi)) { bv = ov; bi = oi; }
    }
    __shared__ double sv[16];
    __shared__ int    si[16];
    const int wave = t >> 6, lane = t & 63;
    if (lane == 0) { sv[wave] = bv; si[wave] = bi; }
    __syncthreads();

    if (t == 0) {
        for (int wv = 1; wv < 16; ++wv)
            if (sv[wv] < bv || (sv[wv] == bv && si[wv] < bi)) { bv = sv[wv]; bi = si[wv]; }
        out[2 * b]     = loc[2 * bi];
        out[2 * b + 1] = loc[2 * bi + 1];

        atomicAdd(acc, sqrt(bv));   // device-scope
        // acq_rel: waits for the acc add to complete before the increment is
        // visible; the winner's acquire sees every block's contribution.
        unsigned old = __hip_atomic_fetch_add(counter, 1u, __ATOMIC_ACQ_REL,
                                              __HIP_MEMORY_SCOPE_AGENT);
        if (old == B - 1) {
            double total = __hip_atomic_load(acc, __ATOMIC_ACQUIRE,
                                             __HIP_MEMORY_SCOPE_AGENT);
            out[2 * B] = (float)(total / (double)B);
        }
    }
}

extern "C" void kernel_launch(void* const* d_in, const int* in_sizes, int n_in,
                              void* d_out, int out_size, void* d_ws, size_t ws_size,
                              hipStream_t stream) {
    const float* x   = (const float*)d_in[0];   // [B, D]
    const float* w   = (const float*)d_in[1];   // [D, M]
    const float* loc = (const float*)d_in[2];   // [M, 2]
    float* out = (float*)d_out;                 // [2*B locations, then loss]

    // ws layout (doubles): S1[D], S2[D], acc; then counter (u32)
    double*   ws_d    = (double*)d_ws;
    double*   S1      = ws_d;
    double*   S2      = ws_d + D;
    double*   acc     = ws_d + 2 * D;
    unsigned* counter = (unsigned*)(ws_d + 2 * D + 1);

    som_stats      <<<D, 256, 0, stream>>>(w, S1, S2, acc, counter);
    som_argmin_loss<<<B, 1024, 0, stream>>>(x, S1, S2, loc, out, acc, counter);
}